// Round 2
// baseline (9754.005 us; speedup 1.0000x reference)
//
#include <hip/hip_runtime.h>
#include <stdint.h>

#define DEV __device__ __forceinline__

typedef unsigned short u16;
typedef unsigned int u32;
using f32x4 = __attribute__((ext_vector_type(4))) float;
using u32x4 = __attribute__((ext_vector_type(4))) u32;
using bf16x8 = __attribute__((ext_vector_type(8))) __bf16;

DEV float b2f(u16 u) { u32 x = ((u32)u) << 16; return __builtin_bit_cast(float, x); }
DEV u16 f2b(float f) {
  u32 x = __builtin_bit_cast(u32, f);
  return (u16)((x + 0x7FFFu + ((x >> 16) & 1u)) >> 16);
}
DEV bf16x8 lds_frag(const u16* p) { return __builtin_bit_cast(bf16x8, *(const u32x4*)p); }
DEV f32x4 mfma16(bf16x8 a, bf16x8 b, f32x4 c) {
  return __builtin_amdgcn_mfma_f32_16x16x32_bf16(a, b, c, 0, 0, 0);
}
DEV float wredmax(float v) {
#pragma unroll
  for (int m = 32; m > 0; m >>= 1) v = fmaxf(v, __shfl_xor(v, m));
  return v;
}
DEV float wredsum(float v) {
#pragma unroll
  for (int m = 32; m > 0; m >>= 1) v += __shfl_xor(v, m);
  return v;
}

// ---------------- LayerNorm: x[16384][512] f32 -> xn bf16 ----------------
__global__ __launch_bounds__(256) void ln_k(const float* __restrict__ x,
                                            const float* __restrict__ gamma,
                                            const float* __restrict__ beta,
                                            u16* __restrict__ xn) {
  int row = blockIdx.x, tid = threadIdx.x;
  int lane = tid & 63, wave = tid >> 6;
  const float* xr = x + (size_t)row * 512;
  float a = xr[2 * tid], b = xr[2 * tid + 1];
  __shared__ float red[8];
  float s = wredsum(a + b);
  if (lane == 0) red[wave] = s;
  __syncthreads();
  float mean = (red[0] + red[1] + red[2] + red[3]) * (1.0f / 512.0f);
  float da = a - mean, db = b - mean;
  float vs = wredsum(da * da + db * db);
  if (lane == 0) red[4 + wave] = vs;
  __syncthreads();
  float var = (red[4] + red[5] + red[6] + red[7]) * (1.0f / 512.0f);
  float rstd = rsqrtf(var + 1e-5f);
  int c = 2 * tid;
  u16 o0 = f2b(da * rstd * gamma[c] + beta[c]);
  u16 o1 = f2b(db * rstd * gamma[c + 1] + beta[c + 1]);
  *(u32*)&xn[(size_t)row * 512 + c] = (u32)o0 | ((u32)o1 << 16);
}

// ------------- transpose f32 [R][C] -> bf16 [C][R] (weights) -------------
__global__ __launch_bounds__(256) void transpose_w(const float* __restrict__ in,
                                                   u16* __restrict__ out, int R, int C) {
  __shared__ float t[64][65];
  int c0 = blockIdx.x * 64, r0 = blockIdx.y * 64;
  int tid = threadIdx.x;
  int r = tid >> 2, cs = (tid & 3) * 16;
  const float* src = in + (size_t)(r0 + r) * C + c0 + cs;
#pragma unroll
  for (int e = 0; e < 16; e++) t[r][cs + e] = src[e];
  __syncthreads();
  int c = tid >> 2, rs = (tid & 3) * 16;
  u16* dst = out + (size_t)(c0 + c) * R + r0 + rs;
#pragma unroll
  for (int e = 0; e < 16; e++) dst[e] = f2b(t[rs + e][c]);
}

// ------------- transpose bf16 k[bh][4096][64] -> kT[bh][64][4096] -------------
__global__ __launch_bounds__(256) void transpose_k(const u16* __restrict__ k,
                                                   u16* __restrict__ kT) {
  __shared__ u16 t[64][72];
  int bh = blockIdx.y, i0 = blockIdx.x * 64;
  int tid = threadIdx.x;
  int r = tid >> 2, ds = (tid & 3) * 16;
  const u16* src = k + (((size_t)bh * 4096) + i0 + r) * 64 + ds;
#pragma unroll
  for (int e = 0; e < 16; e++) t[r][ds + e] = src[e];
  __syncthreads();
  int d = tid >> 2, is = (tid & 3) * 16;
  u16* dst = kT + ((size_t)bh * 64 + d) * 4096 + i0 + is;
#pragma unroll
  for (int e = 0; e < 16; e++) dst[e] = t[is + e][d];
}

// ---------------- landmark means: src bf16 [bh][4096][64] -> dst f32 [bh][256][64] ----------------
__global__ __launch_bounds__(256) void landmark_mean(const u16* __restrict__ src,
                                                     float* __restrict__ dst) {
  int gid = blockIdx.x * 4 + (threadIdx.x >> 6);
  int lane = threadIdx.x & 63;
  int bh = gid >> 8, lm = gid & 255;
  const u16* p = src + (((size_t)bh * 4096) + lm * 16) * 64 + lane;
  float s = 0.f;
#pragma unroll
  for (int t = 0; t < 16; t++) s += b2f(p[t * 64]);
  dst[((size_t)bh * 256 + lm) * 64 + lane] = s * (1.0f / 16.0f);
}

// ---------------- big bf16 NT GEMM: C = A[M][K] * Bt[N][K]^T ----------------
// MODE 0: qkv epilogue (scatter to q/k/v bf16, q scaled 0.125)
// MODE 1: out-proj epilogue (A = out_h custom layout; out = x + C + bias, f32)
template <int MODE>
__global__ __launch_bounds__(256) void gemm_bf16_nt(
    const u16* __restrict__ A, const u16* __restrict__ Bt, int K,
    u16* __restrict__ oq, u16* __restrict__ ok, u16* __restrict__ ov,
    const float* __restrict__ xres, const float* __restrict__ bias,
    float* __restrict__ oc) {
  constexpr int BM = 128, BN = 128, BK = 32, LDT = BK + 8;
  constexpr int SMEM = (MODE == 1) ? (128 * 132 * 4) : (128 * 136 * 2);
  __shared__ __align__(16) char smem[SMEM];
  u16(*Al)[LDT] = (u16(*)[LDT])smem;
  u16(*Bl)[LDT] = (u16(*)[LDT])(smem + BM * LDT * 2);
  int tid = threadIdx.x;
  int lane = tid & 63, wave = tid >> 6;
  int bm = blockIdx.x * BM, bn = blockIdx.y * BN;
  int wm = (wave >> 1) * 64, wn = (wave & 1) * 64;
  f32x4 acc[4][4] = {};
  for (int kt = 0; kt < K; kt += BK) {
    __syncthreads();
#pragma unroll
    for (int c = 0; c < 2; c++) {
      int chunk = tid + c * 256;
      int r = chunk >> 2, kc = (chunk & 3) * 8;
      const u16* src;
      if (MODE == 0) {
        src = A + (size_t)(bm + r) * K + kt + kc;
      } else {
        int m = bm + r, kk = kt + kc;
        src = A + ((((size_t)(m >> 12)) * 8 + (kk >> 6)) * 4096 + (m & 4095)) * 64 + (kk & 63);
      }
      *(u32x4*)&Al[r][kc] = *(const u32x4*)src;
      const u16* srcb = Bt + (size_t)(bn + r) * K + kt + kc;
      *(u32x4*)&Bl[r][kc] = *(const u32x4*)srcb;
    }
    __syncthreads();
    bf16x8 af[4], bf_[4];
#pragma unroll
    for (int i = 0; i < 4; i++) af[i] = lds_frag(&Al[wm + i * 16 + (lane & 15)][8 * (lane >> 4)]);
#pragma unroll
    for (int i = 0; i < 4; i++) bf_[i] = lds_frag(&Bl[wn + i * 16 + (lane & 15)][8 * (lane >> 4)]);
#pragma unroll
    for (int mi = 0; mi < 4; mi++)
#pragma unroll
      for (int ni = 0; ni < 4; ni++) acc[mi][ni] = mfma16(af[mi], bf_[ni], acc[mi][ni]);
  }
  __syncthreads();
  if (MODE == 0) {
    u16(*Cl)[136] = (u16(*)[136])smem;
    int tensor = bn / 512;
    float scale = (tensor == 0) ? 0.125f : 1.0f;
#pragma unroll
    for (int mi = 0; mi < 4; mi++)
      for (int ni = 0; ni < 4; ni++)
        for (int r = 0; r < 4; r++) {
          int row = wm + mi * 16 + 4 * (lane >> 4) + r;
          int col = wn + ni * 16 + (lane & 15);
          Cl[row][col] = f2b(acc[mi][ni][r] * scale);
        }
    __syncthreads();
    int half = tid >> 7, r = tid & 127;
    int m = bm + r, b = m >> 12, i = m & 4095;
    int cw = (bn % 512) + half * 64;
    int h = cw >> 6;
    u16* base = (tensor == 0) ? oq : (tensor == 1 ? ok : ov);
    u16* dst = base + (((size_t)(b * 8 + h)) * 4096 + i) * 64;
#pragma unroll
    for (int j = 0; j < 64; j += 8) *(u32x4*)(dst + j) = *(const u32x4*)&Cl[r][half * 64 + j];
  } else {
    float(*Cf)[132] = (float(*)[132])smem;
#pragma unroll
    for (int mi = 0; mi < 4; mi++)
      for (int ni = 0; ni < 4; ni++)
        for (int r = 0; r < 4; r++) {
          int row = wm + mi * 16 + 4 * (lane >> 4) + r;
          int col = wn + ni * 16 + (lane & 15);
          Cf[row][col] = acc[mi][ni][r];
        }
    __syncthreads();
    int r = tid >> 1, seg = (tid & 1) * 64;
    int m = bm + r;
    const float* xr = xres + (size_t)m * 512 + bn + seg;
    const float* br = bias + bn + seg;
    float* orow = oc + (size_t)m * 512 + bn + seg;
#pragma unroll
    for (int j = 0; j < 64; j += 4) {
      f32x4 cv = *(const f32x4*)&Cf[r][seg + j];
      f32x4 xv = *(const f32x4*)&xr[j];
      f32x4 bv = *(const f32x4*)&br[j];
      cv = cv + xv + bv;
      *(f32x4*)&orow[j] = cv;
    }
  }
}

// ---------------- batched f32-in NT GEMM with hi/lo bf16 split ----------------
// C[m][n] = alpha * sum_k A[m][k] * (cdiag*(k==n) + sgn*B[n][k]);  optional C and CT outputs.
__global__ __launch_bounds__(256) void gemm_f32_nt(
    const float* __restrict__ A, const float* __restrict__ B, float* __restrict__ C,
    float* __restrict__ CT, int M, int N, int K, int sA, int sB, int sC, int sCT,
    float cdiag, float sgn, float alpha, int wrC, int wrCT) {
  __shared__ u16 Ah[64][40], Alo[64][40], Bh[64][40], Blo[64][40];
  int bz = blockIdx.z;
  const float* Ab = A + (size_t)bz * sA;
  const float* Bb = B + (size_t)bz * sB;
  int tid = threadIdx.x, lane = tid & 63, wave = tid >> 6;
  int bm = blockIdx.x * 64, bn = blockIdx.y * 64;
  int wm = (wave >> 1) * 32, wn = (wave & 1) * 32;
  f32x4 acc[2][2] = {};
  for (int kt = 0; kt < K; kt += 32) {
    __syncthreads();
    int r = tid >> 2, kc = (tid & 3) * 8;
    {
      const float* s = Ab + (size_t)(bm + r) * K + kt + kc;
#pragma unroll
      for (int e = 0; e < 8; e++) {
        float v = s[e];
        u16 hi = f2b(v);
        Ah[r][kc + e] = hi;
        Alo[r][kc + e] = f2b(v - b2f(hi));
      }
    }
    {
      const float* s = Bb + (size_t)(bn + r) * K + kt + kc;
      int nglob = bn + r;
#pragma unroll
      for (int e = 0; e < 8; e++) {
        int kglob = kt + kc + e;
        float v = sgn * s[e] + ((kglob == nglob) ? cdiag : 0.0f);
        u16 hi = f2b(v);
        Bh[r][kc + e] = hi;
        Blo[r][kc + e] = f2b(v - b2f(hi));
      }
    }
    __syncthreads();
    bf16x8 ah[2], al[2], bh[2], bl[2];
#pragma unroll
    for (int i = 0; i < 2; i++) {
      int ro = wm + i * 16 + (lane & 15), ko = 8 * (lane >> 4);
      ah[i] = lds_frag(&Ah[ro][ko]);
      al[i] = lds_frag(&Alo[ro][ko]);
    }
#pragma unroll
    for (int i = 0; i < 2; i++) {
      int ro = wn + i * 16 + (lane & 15), ko = 8 * (lane >> 4);
      bh[i] = lds_frag(&Bh[ro][ko]);
      bl[i] = lds_frag(&Blo[ro][ko]);
    }
#pragma unroll
    for (int mi = 0; mi < 2; mi++)
#pragma unroll
      for (int ni = 0; ni < 2; ni++) {
        acc[mi][ni] = mfma16(ah[mi], bh[ni], acc[mi][ni]);
        acc[mi][ni] = mfma16(ah[mi], bl[ni], acc[mi][ni]);
        acc[mi][ni] = mfma16(al[mi], bh[ni], acc[mi][ni]);
      }
  }
#pragma unroll
  for (int mi = 0; mi < 2; mi++)
#pragma unroll
    for (int ni = 0; ni < 2; ni++) {
      int r0 = wm + mi * 16 + 4 * (lane >> 4);
      int col = wn + ni * 16 + (lane & 15);
      f32x4 v = acc[mi][ni] * alpha;
      if (wrC) {
        float* c = C + (size_t)bz * sC;
#pragma unroll
        for (int r = 0; r < 4; r++) c[(size_t)(bm + r0 + r) * N + bn + col] = v[r];
      }
      if (wrCT) {
        float* ct = CT + (size_t)bz * sCT + (size_t)(bn + col) * M + bm + r0;
        *(f32x4*)ct = v;
      }
    }
}

// ---------------- row softmax over 256 (in place), wave per row ----------------
__global__ __launch_bounds__(256) void softmax256(float* __restrict__ S) {
  int row = blockIdx.x * 4 + (threadIdx.x >> 6);
  int lane = threadIdx.x & 63;
  float* r = S + (size_t)row * 256;
  f32x4 vv = *(f32x4*)&r[lane * 4];
  float mx = wredmax(fmaxf(fmaxf(vv[0], vv[1]), fmaxf(vv[2], vv[3])));
  vv[0] = __expf(vv[0] - mx);
  vv[1] = __expf(vv[1] - mx);
  vv[2] = __expf(vv[2] - mx);
  vv[3] = __expf(vv[3] - mx);
  float sm = wredsum(vv[0] + vv[1] + vv[2] + vv[3]);
  vv *= (1.0f / sm);
  *(f32x4*)&r[lane * 4] = vv;
}

// ---------------- pinv scale: global max row-sum / col-sum (entries >= 0) ----------------
__global__ __launch_bounds__(256) void pinv_scale(const float* __restrict__ mat,
                                                  float* __restrict__ scal) {
  int bh = blockIdx.x, tid = threadIdx.x;
  int lane = tid & 63, wave = tid >> 6;
  const float* m = mat + (size_t)bh * 65536;
  float cs = 0.f, rs = 0.f;
  for (int i = 0; i < 256; i++) cs += m[i * 256 + tid];
  for (int j = 0; j < 256; j++) rs += m[tid * 256 + j];
  __shared__ float red[8];
  float cm = wredmax(cs);
  float rm = wredmax(rs);
  if (lane == 0) { red[wave] = cm; red[4 + wave] = rm; }
  __syncthreads();
  if (tid == 0) {
    float a = fmaxf(fmaxf(red[0], red[1]), fmaxf(red[2], red[3]));
    float b = fmaxf(fmaxf(red[4], red[5]), fmaxf(red[6], red[7]));
    atomicMax((int*)&scal[0], __float_as_int(a));
    atomicMax((int*)&scal[1], __float_as_int(b));
  }
}

__global__ __launch_bounds__(256) void pinv_init(const float* __restrict__ mat,
                                                 const float* __restrict__ scal,
                                                 float* __restrict__ z,
                                                 float* __restrict__ zT) {
  size_t idx = (size_t)blockIdx.x * 256 + threadIdx.x;
  int bh = (int)(idx >> 16);
  int i = (int)((idx >> 8) & 255), j = (int)(idx & 255);
  float s = 1.0f / (scal[0] * scal[1]);
  float val = mat[idx] * s;
  zT[idx] = val;
  z[((size_t)bh << 16) + ((size_t)j << 8) + i] = val;
}

// ---------------- fused attn3 @ v: online softmax over 4096, w3T[bh][64][256] ----------------
__global__ __launch_bounds__(256) void attn3_pv(const float* __restrict__ q_l,
                                                const u16* __restrict__ kT,
                                                const u16* __restrict__ v,
                                                float* __restrict__ w3T) {
  __shared__ u16 kc[64][64];
  __shared__ u16 vc[64][64];
  __shared__ float ql[4][64];
  __shared__ float pl[4][64];
  int tid = threadIdx.x, lane = tid & 63, wave = tid >> 6;
  int bh = blockIdx.y;
  int i = blockIdx.x * 4 + wave;
  ql[wave][lane] = q_l[((size_t)bh * 256 + i) * 64 + lane];
  const u16* kTb = kT + (size_t)bh * 64 * 4096;
  const u16* vb = v + (size_t)bh * 4096 * 64;
  float m = -1e30f, l = 0.f, acc = 0.f;
  for (int j0 = 0; j0 < 4096; j0 += 64) {
    __syncthreads();
#pragma unroll
    for (int c = 0; c < 2; c++) {
      int chunk = tid + c * 256;
      int d = chunk >> 3, js = (chunk & 7) * 8;
      *(u32x4*)&kc[d][js] = *(const u32x4*)(kTb + (size_t)d * 4096 + j0 + js);
      *(u32x4*)&vc[d][js] = *(const u32x4*)(vb + (size_t)(j0 + d) * 64 + js);
    }
    __syncthreads();
    float s = 0.f;
#pragma unroll
    for (int d = 0; d < 64; d++) s += ql[wave][d] * b2f(kc[d][lane]);
    float mc = wredmax(s);
    float mnew = fmaxf(m, mc);
    float corr = __expf(m - mnew);
    float p = __expf(s - mnew);
    float psum = wredsum(p);
    l = l * corr + psum;
    acc *= corr;
    pl[wave][lane] = p;
#pragma unroll
    for (int j = 0; j < 64; j++) acc += pl[wave][j] * b2f(vc[j][lane]);
    m = mnew;
  }
  w3T[((size_t)bh * 64 + lane) * 256 + i] = acc / l;
}

// ---------------- fused attn1 @ zw + depthwise-conv residual -> out_h bf16 ----------------
__global__ __launch_bounds__(256) void attn1_pv(const u16* __restrict__ q,
                                                const float* __restrict__ k_l,
                                                const float* __restrict__ zw,
                                                const u16* __restrict__ v,
                                                const float* __restrict__ rker,
                                                u16* __restrict__ out_h) {
  __shared__ u16 klT[64][256];
  __shared__ u16 zwl[256][64];
  __shared__ float pl[4][256];
  __shared__ float ql[4][64];
  __shared__ float ker[33];
  int tid = threadIdx.x, lane = tid & 63, wave = tid >> 6;
  int bh = blockIdx.y, h = bh & 7;
  int i0 = blockIdx.x * 32;
  {
    int j = tid;
    const float* src = k_l + ((size_t)bh * 256 + j) * 64;
#pragma unroll
    for (int d = 0; d < 64; d += 4) {
      f32x4 vv = *(const f32x4*)&src[d];
      klT[d][j] = f2b(vv[0]);
      klT[d + 1][j] = f2b(vv[1]);
      klT[d + 2][j] = f2b(vv[2]);
      klT[d + 3][j] = f2b(vv[3]);
    }
    const float* szw = zw + ((size_t)bh * 256 + j) * 64;
#pragma unroll
    for (int d = 0; d < 64; d += 4) {
      f32x4 vv = *(const f32x4*)&szw[d];
      *(u32*)&zwl[j][d] = (u32)f2b(vv[0]) | ((u32)f2b(vv[1]) << 16);
      *(u32*)&zwl[j][d + 2] = (u32)f2b(vv[2]) | ((u32)f2b(vv[3]) << 16);
    }
    if (tid < 33) ker[tid] = rker[h * 33 + tid];
  }
  __syncthreads();
  const u16* qb = q + ((size_t)bh * 4096) * 64;
  const u16* vb = v + ((size_t)bh * 4096) * 64 + lane;
  for (int rr = 0; rr < 8; rr++) {
    int i = i0 + wave * 8 + rr;
    ql[wave][lane] = b2f(qb[(size_t)i * 64 + lane]);
    float s0 = 0, s1 = 0, s2 = 0, s3 = 0;
#pragma unroll
    for (int d = 0; d < 64; d++) {
      float qv = ql[wave][d];
      const u16* kr = &klT[d][lane * 4];
      s0 += qv * b2f(kr[0]);
      s1 += qv * b2f(kr[1]);
      s2 += qv * b2f(kr[2]);
      s3 += qv * b2f(kr[3]);
    }
    float mx = wredmax(fmaxf(fmaxf(s0, s1), fmaxf(s2, s3)));
    float p0 = __expf(s0 - mx), p1 = __expf(s1 - mx), p2 = __expf(s2 - mx), p3 = __expf(s3 - mx);
    float lsum = wredsum(p0 + p1 + p2 + p3);
    f32x4 pv = {p0, p1, p2, p3};
    *(f32x4*)&pl[wave][lane * 4] = pv;
    float acc = 0.f;
#pragma unroll
    for (int j = 0; j < 256; j++) acc += pl[wave][j] * b2f(zwl[j][lane]);
    acc /= lsum;
    float res = 0.f;
#pragma unroll
    for (int t = 0; t < 33; t++) {
      int sr = i + t - 16;
      if (sr >= 0 && sr < 4096) res += ker[t] * b2f(vb[(size_t)sr * 64]);
    }
    out_h[((size_t)bh * 4096 + i) * 64 + lane] = f2b(acc + res);
  }
}

extern "C" void kernel_launch(void* const* d_in, const int* in_sizes, int n_in,
                              void* d_out, int out_size, void* d_ws, size_t ws_size,
                              hipStream_t stream) {
  (void)in_sizes; (void)n_in; (void)out_size;
  const float* x = (const float*)d_in[0];
  const float* w_qkv = (const float*)d_in[1];
  const float* w_out = (const float*)d_in[2];
  const float* b_out = (const float*)d_in[3];
  const float* res_k = (const float*)d_in[4];
  const float* gamma = (const float*)d_in[5];
  const float* beta = (const float*)d_in[6];
  float* out = (float*)d_out;

  char* p = (char*)d_ws;
  auto alloc = [&](size_t bytes) {
    char* r = p;
    p += (bytes + 255) & ~(size_t)255;
    return r;
  };
  const size_t BH = 32;
  u16* xn = (u16*)alloc(BH * 4096 * 64 * 2);  // aliased: kT after qkv
  u16* kT = xn;
  u16* wTq = (u16*)alloc(1536 * 512 * 2);
  u16* wTo = (u16*)alloc(512 * 512 * 2);
  u16* q = (u16*)alloc(BH * 4096 * 64 * 2);
  u16* k = (u16*)alloc(BH * 4096 * 64 * 2);
  u16* v = (u16*)alloc(BH * 4096 * 64 * 2);
  float* q_l = (float*)alloc(BH * 256 * 64 * 4);
  float* k_l = (float*)alloc(BH * 256 * 64 * 4);
  float* mat = (float*)alloc(BH * 65536 * 4);
  float* z = (float*)alloc(BH * 65536 * 4);
  float* zT = (float*)alloc(BH * 65536 * 4);
  float* znew = (float*)alloc(BH * 65536 * 4);
  float* znewT = (float*)alloc(BH * 65536 * 4);
  char* slotB = alloc(4 * BH * 65536 * 4);  // mz,mzT,t2T,t4T; aliased: out_h
  float* mz = (float*)slotB;
  float* mzT = mz + BH * 65536;
  float* t2T = mzT + BH * 65536;
  float* t4T = t2T + BH * 65536;
  u16* out_h = (u16*)slotB;
  float* w3T = (float*)alloc(BH * 64 * 256 * 4);
  float* zw = (float*)alloc(BH * 256 * 64 * 4);
  float* scal = (float*)alloc(256);
  if ((size_t)(p - (char*)d_ws) > ws_size) return;  // insufficient workspace

  hipMemsetAsync(scal, 0, 8, stream);
  ln_k<<<16384, 256, 0, stream>>>(x, gamma, beta, xn);
  transpose_w<<<dim3(24, 8), 256, 0, stream>>>(w_qkv, wTq, 512, 1536);
  transpose_w<<<dim3(8, 8), 256, 0, stream>>>(w_out, wTo, 512, 512);
  gemm_bf16_nt<0><<<dim3(128, 12), 256, 0, stream>>>(xn, wTq, 512, q, k, v, nullptr,
                                                     nullptr, nullptr);
  landmark_mean<<<2048, 256, 0, stream>>>(q, q_l);
  landmark_mean<<<2048, 256, 0, stream>>>(k, k_l);
  transpose_k<<<dim3(64, 32), 256, 0, stream>>>(k, kT);
  // attn2 logits: mat = q_l @ k_l^T
  gemm_f32_nt<<<dim3(4, 4, 32), 256, 0, stream>>>(q_l, k_l, mat, nullptr, 256, 256, 64,
                                                  16384, 16384, 65536, 0, 0.f, 1.f, 1.f, 1, 0);
  softmax256<<<2048, 256, 0, stream>>>(mat);
  pinv_scale<<<32, 256, 0, stream>>>(mat, scal);
  pinv_init<<<8192, 256, 0, stream>>>(mat, scal, z, zT);
  float* zc = z; float* zcT = zT; float* zn = znew; float* znT = znewT;
  for (int it = 0; it < 6; it++) {
    gemm_f32_nt<<<dim3(4, 4, 32), 256, 0, stream>>>(mat, zcT, mz, mzT, 256, 256, 256,
                                                    65536, 65536, 65536, 65536, 0.f, 1.f, 1.f, 1, 1);
    gemm_f32_nt<<<dim3(4, 4, 32), 256, 0, stream>>>(mz, mzT, nullptr, t2T, 256, 256, 256,
                                                    65536, 65536, 65536, 65536, 7.f, -1.f, 1.f, 0, 1);
    gemm_f32_nt<<<dim3(4, 4, 32), 256, 0, stream>>>(mz, t2T, nullptr, t4T, 256, 256, 256,
                                                    65536, 65536, 65536, 65536, 15.f, -1.f, 1.f, 0, 1);
    gemm_f32_nt<<<dim3(4, 4, 32), 256, 0, stream>>>(zc, t4T, zn, znT, 256, 256, 256,
                                                    65536, 65536, 65536, 65536, 13.f, -1.f, 0.25f, 1, 1);
    float* t;
    t = zc; zc = zn; zn = t;
    t = zcT; zcT = znT; znT = t;
  }
  attn3_pv<<<dim3(64, 32), 256, 0, stream>>>(q_l, kT, v, w3T);
  // zw = z @ w3
  gemm_f32_nt<<<dim3(4, 1, 32), 256, 0, stream>>>(zc, w3T, zw, nullptr, 256, 64, 256,
                                                  65536, 16384, 16384, 0, 0.f, 1.f, 1.f, 1, 0);
  attn1_pv<<<dim3(128, 32), 256, 0, stream>>>(q, k_l, zw, v, res_k, out_h);
  gemm_bf16_nt<1><<<dim3(128, 4), 256, 0, stream>>>(out_h, wTo, 512, nullptr, nullptr,
                                                    nullptr, x, b_out, out);
}

// Round 3
// 690.253 us; speedup vs baseline: 14.1311x; 14.1311x over previous
//
#include <hip/hip_runtime.h>
#include <stdint.h>

#define DEV __device__ __forceinline__

typedef unsigned short u16;
typedef unsigned int u32;
using f32x4 = __attribute__((ext_vector_type(4))) float;
using u32x4 = __attribute__((ext_vector_type(4))) u32;
using bf16x8 = __attribute__((ext_vector_type(8))) __bf16;

DEV float b2f(u16 u) { u32 x = ((u32)u) << 16; return __builtin_bit_cast(float, x); }
DEV u16 f2b(float f) {
  u32 x = __builtin_bit_cast(u32, f);
  return (u16)((x + 0x7FFFu + ((x >> 16) & 1u)) >> 16);
}
DEV u32 pk2(float a, float b) { return (u32)f2b(a) | ((u32)f2b(b) << 16); }
DEV bf16x8 lds_frag(const u16* p) { return __builtin_bit_cast(bf16x8, *(const u32x4*)p); }
DEV f32x4 mfma16(bf16x8 a, bf16x8 b, f32x4 c) {
  return __builtin_amdgcn_mfma_f32_16x16x32_bf16(a, b, c, 0, 0, 0);
}
DEV float wredmax(float v) {
#pragma unroll
  for (int m = 32; m > 0; m >>= 1) v = fmaxf(v, __shfl_xor(v, m));
  return v;
}
DEV float wredsum(float v) {
#pragma unroll
  for (int m = 32; m > 0; m >>= 1) v += __shfl_xor(v, m);
  return v;
}

// ---------------- LayerNorm: x[16384][512] f32 -> xn bf16 ----------------
__global__ __launch_bounds__(256) void ln_k(const float* __restrict__ x,
                                            const float* __restrict__ gamma,
                                            const float* __restrict__ beta,
                                            u16* __restrict__ xn) {
  int row = blockIdx.x, tid = threadIdx.x;
  int lane = tid & 63, wave = tid >> 6;
  const float* xr = x + (size_t)row * 512;
  float a = xr[2 * tid], b = xr[2 * tid + 1];
  __shared__ float red[8];
  float s = wredsum(a + b);
  if (lane == 0) red[wave] = s;
  __syncthreads();
  float mean = (red[0] + red[1] + red[2] + red[3]) * (1.0f / 512.0f);
  float da = a - mean, db = b - mean;
  float vs = wredsum(da * da + db * db);
  if (lane == 0) red[4 + wave] = vs;
  __syncthreads();
  float var = (red[4] + red[5] + red[6] + red[7]) * (1.0f / 512.0f);
  float rstd = rsqrtf(var + 1e-5f);
  int c = 2 * tid;
  u16 o0 = f2b(da * rstd * gamma[c] + beta[c]);
  u16 o1 = f2b(db * rstd * gamma[c + 1] + beta[c + 1]);
  *(u32*)&xn[(size_t)row * 512 + c] = (u32)o0 | ((u32)o1 << 16);
}

// ------------- transpose f32 [R][C] -> bf16 [C][R] (weights) -------------
__global__ __launch_bounds__(256) void transpose_w(const float* __restrict__ in,
                                                   u16* __restrict__ out, int R, int C) {
  __shared__ float t[64][65];
  int c0 = blockIdx.x * 64, r0 = blockIdx.y * 64;
  int tid = threadIdx.x;
  int r = tid >> 2, cs = (tid & 3) * 16;
  const float* src = in + (size_t)(r0 + r) * C + c0 + cs;
#pragma unroll
  for (int e = 0; e < 16; e++) t[r][cs + e] = src[e];
  __syncthreads();
  int c = tid >> 2, rs = (tid & 3) * 16;
  u16* dst = out + (size_t)(c0 + c) * R + r0 + rs;
#pragma unroll
  for (int e = 0; e < 16; e++) dst[e] = f2b(t[rs + e][c]);
}

// ------------- transpose bf16 src[bh][4096][64] -> dst[bh][64][4096] -------------
__global__ __launch_bounds__(256) void transpose_k(const u16* __restrict__ k,
                                                   u16* __restrict__ kT) {
  __shared__ u16 t[64][72];
  int bh = blockIdx.y, i0 = blockIdx.x * 64;
  int tid = threadIdx.x;
  int r = tid >> 2, ds = (tid & 3) * 16;
  const u16* src = k + (((size_t)bh * 4096) + i0 + r) * 64 + ds;
#pragma unroll
  for (int e = 0; e < 16; e++) t[r][ds + e] = src[e];
  __syncthreads();
  int d = tid >> 2, is = (tid & 3) * 16;
  u16* dst = kT + ((size_t)bh * 64 + d) * 4096 + i0 + is;
#pragma unroll
  for (int e = 0; e < 16; e++) dst[e] = t[is + e][d];
}

// ---------------- landmark means: src bf16 [bh][4096][64] -> dst f32 [bh][256][64] ----------------
__global__ __launch_bounds__(256) void landmark_mean(const u16* __restrict__ src,
                                                     float* __restrict__ dst) {
  int gid = blockIdx.x * 4 + (threadIdx.x >> 6);
  int lane = threadIdx.x & 63;
  int bh = gid >> 8, lm = gid & 255;
  const u16* p = src + (((size_t)bh * 4096) + lm * 16) * 64 + lane;
  float s = 0.f;
#pragma unroll
  for (int t = 0; t < 16; t++) s += b2f(p[t * 64]);
  dst[((size_t)bh * 256 + lm) * 64 + lane] = s * (1.0f / 16.0f);
}

// ---------------- big bf16 NT GEMM: C = A[M][K] * Bt[N][K]^T ----------------
template <int MODE>
__global__ __launch_bounds__(256) void gemm_bf16_nt(
    const u16* __restrict__ A, const u16* __restrict__ Bt, int K,
    u16* __restrict__ oq, u16* __restrict__ ok, u16* __restrict__ ov,
    const float* __restrict__ xres, const float* __restrict__ bias,
    float* __restrict__ oc) {
  constexpr int BM = 128, BN = 128, BK = 32, LDT = BK + 8;
  constexpr int SMEM = (MODE == 1) ? (128 * 132 * 4) : (128 * 136 * 2);
  __shared__ __align__(16) char smem[SMEM];
  u16(*Al)[LDT] = (u16(*)[LDT])smem;
  u16(*Bl)[LDT] = (u16(*)[LDT])(smem + BM * LDT * 2);
  int tid = threadIdx.x;
  int lane = tid & 63, wave = tid >> 6;
  int bm = blockIdx.x * BM, bn = blockIdx.y * BN;
  int wm = (wave >> 1) * 64, wn = (wave & 1) * 64;
  f32x4 acc[4][4] = {};
  for (int kt = 0; kt < K; kt += BK) {
    __syncthreads();
#pragma unroll
    for (int c = 0; c < 2; c++) {
      int chunk = tid + c * 256;
      int r = chunk >> 2, kc = (chunk & 3) * 8;
      const u16* src;
      if (MODE == 0) {
        src = A + (size_t)(bm + r) * K + kt + kc;
      } else {
        int m = bm + r, kk = kt + kc;
        src = A + ((((size_t)(m >> 12)) * 8 + (kk >> 6)) * 4096 + (m & 4095)) * 64 + (kk & 63);
      }
      *(u32x4*)&Al[r][kc] = *(const u32x4*)src;
      const u16* srcb = Bt + (size_t)(bn + r) * K + kt + kc;
      *(u32x4*)&Bl[r][kc] = *(const u32x4*)srcb;
    }
    __syncthreads();
    bf16x8 af[4], bf_[4];
#pragma unroll
    for (int i = 0; i < 4; i++) af[i] = lds_frag(&Al[wm + i * 16 + (lane & 15)][8 * (lane >> 4)]);
#pragma unroll
    for (int i = 0; i < 4; i++) bf_[i] = lds_frag(&Bl[wn + i * 16 + (lane & 15)][8 * (lane >> 4)]);
#pragma unroll
    for (int mi = 0; mi < 4; mi++)
#pragma unroll
      for (int ni = 0; ni < 4; ni++) acc[mi][ni] = mfma16(af[mi], bf_[ni], acc[mi][ni]);
  }
  __syncthreads();
  if (MODE == 0) {
    u16(*Cl)[136] = (u16(*)[136])smem;
    int tensor = bn / 512;
    float scale = (tensor == 0) ? 0.125f : 1.0f;
#pragma unroll
    for (int mi = 0; mi < 4; mi++)
      for (int ni = 0; ni < 4; ni++)
        for (int r = 0; r < 4; r++) {
          int row = wm + mi * 16 + 4 * (lane >> 4) + r;
          int col = wn + ni * 16 + (lane & 15);
          Cl[row][col] = f2b(acc[mi][ni][r] * scale);
        }
    __syncthreads();
    int half = tid >> 7, r = tid & 127;
    int m = bm + r, b = m >> 12, i = m & 4095;
    int cw = (bn % 512) + half * 64;
    int h = cw >> 6;
    u16* base = (tensor == 0) ? oq : (tensor == 1 ? ok : ov);
    u16* dst = base + (((size_t)(b * 8 + h)) * 4096 + i) * 64;
#pragma unroll
    for (int j = 0; j < 64; j += 8) *(u32x4*)(dst + j) = *(const u32x4*)&Cl[r][half * 64 + j];
  } else {
    float(*Cf)[132] = (float(*)[132])smem;
#pragma unroll
    for (int mi = 0; mi < 4; mi++)
      for (int ni = 0; ni < 4; ni++)
        for (int r = 0; r < 4; r++) {
          int row = wm + mi * 16 + 4 * (lane >> 4) + r;
          int col = wn + ni * 16 + (lane & 15);
          Cf[row][col] = acc[mi][ni][r];
        }
    __syncthreads();
    int r = tid >> 1, seg = (tid & 1) * 64;
    int m = bm + r;
    const float* xr = xres + (size_t)m * 512 + bn + seg;
    const float* br = bias + bn + seg;
    float* orow = oc + (size_t)m * 512 + bn + seg;
#pragma unroll
    for (int j = 0; j < 64; j += 4) {
      f32x4 cv = *(const f32x4*)&Cf[r][seg + j];
      f32x4 xv = *(const f32x4*)&xr[j];
      f32x4 bv = *(const f32x4*)&br[j];
      cv = cv + xv + bv;
      *(f32x4*)&orow[j] = cv;
    }
  }
}

// ---------------- batched f32-in NT GEMM with hi/lo bf16 split ----------------
__global__ __launch_bounds__(256) void gemm_f32_nt(
    const float* __restrict__ A, const float* __restrict__ B, float* __restrict__ C,
    float* __restrict__ CT, int M, int N, int K, int sA, int sB, int sC, int sCT,
    float cdiag, float sgn, float alpha, int wrC, int wrCT) {
  __shared__ u16 Ah[64][40], Alo[64][40], Bh[64][40], Blo[64][40];
  int bz = blockIdx.z;
  const float* Ab = A + (size_t)bz * sA;
  const float* Bb = B + (size_t)bz * sB;
  int tid = threadIdx.x, lane = tid & 63, wave = tid >> 6;
  int bm = blockIdx.x * 64, bn = blockIdx.y * 64;
  int wm = (wave >> 1) * 32, wn = (wave & 1) * 32;
  f32x4 acc[2][2] = {};
  for (int kt = 0; kt < K; kt += 32) {
    __syncthreads();
    int r = tid >> 2, kc = (tid & 3) * 8;
    {
      const float* s = Ab + (size_t)(bm + r) * K + kt + kc;
#pragma unroll
      for (int e = 0; e < 8; e++) {
        float v = s[e];
        u16 hi = f2b(v);
        Ah[r][kc + e] = hi;
        Alo[r][kc + e] = f2b(v - b2f(hi));
      }
    }
    {
      const float* s = Bb + (size_t)(bn + r) * K + kt + kc;
      int nglob = bn + r;
#pragma unroll
      for (int e = 0; e < 8; e++) {
        int kglob = kt + kc + e;
        float v = sgn * s[e] + ((kglob == nglob) ? cdiag : 0.0f);
        u16 hi = f2b(v);
        Bh[r][kc + e] = hi;
        Blo[r][kc + e] = f2b(v - b2f(hi));
      }
    }
    __syncthreads();
    bf16x8 ah[2], al[2], bh[2], bl[2];
#pragma unroll
    for (int i = 0; i < 2; i++) {
      int ro = wm + i * 16 + (lane & 15), ko = 8 * (lane >> 4);
      ah[i] = lds_frag(&Ah[ro][ko]);
      al[i] = lds_frag(&Alo[ro][ko]);
    }
#pragma unroll
    for (int i = 0; i < 2; i++) {
      int ro = wn + i * 16 + (lane & 15), ko = 8 * (lane >> 4);
      bh[i] = lds_frag(&Bh[ro][ko]);
      bl[i] = lds_frag(&Blo[ro][ko]);
    }
#pragma unroll
    for (int mi = 0; mi < 2; mi++)
#pragma unroll
      for (int ni = 0; ni < 2; ni++) {
        acc[mi][ni] = mfma16(ah[mi], bh[ni], acc[mi][ni]);
        acc[mi][ni] = mfma16(ah[mi], bl[ni], acc[mi][ni]);
        acc[mi][ni] = mfma16(al[mi], bh[ni], acc[mi][ni]);
      }
  }
#pragma unroll
  for (int mi = 0; mi < 2; mi++)
#pragma unroll
    for (int ni = 0; ni < 2; ni++) {
      int r0 = wm + mi * 16 + 4 * (lane >> 4);
      int col = wn + ni * 16 + (lane & 15);
      f32x4 v = acc[mi][ni] * alpha;
      if (wrC) {
        float* c = C + (size_t)bz * sC;
#pragma unroll
        for (int r = 0; r < 4; r++) c[(size_t)(bm + r0 + r) * N + bn + col] = v[r];
      }
      if (wrCT) {
        float* ct = CT + (size_t)bz * sCT + (size_t)(bn + col) * M + bm + r0;
        *(f32x4*)ct = v;
      }
    }
}

// ---------------- row softmax over 256 (in place), wave per row ----------------
__global__ __launch_bounds__(256) void softmax256(float* __restrict__ S) {
  int row = blockIdx.x * 4 + (threadIdx.x >> 6);
  int lane = threadIdx.x & 63;
  float* r = S + (size_t)row * 256;
  f32x4 vv = *(f32x4*)&r[lane * 4];
  float mx = wredmax(fmaxf(fmaxf(vv[0], vv[1]), fmaxf(vv[2], vv[3])));
  vv[0] = __expf(vv[0] - mx);
  vv[1] = __expf(vv[1] - mx);
  vv[2] = __expf(vv[2] - mx);
  vv[3] = __expf(vv[3] - mx);
  float sm = wredsum(vv[0] + vv[1] + vv[2] + vv[3]);
  vv *= (1.0f / sm);
  *(f32x4*)&r[lane * 4] = vv;
}

// ---------------- pinv scale ----------------
__global__ __launch_bounds__(256) void pinv_scale(const float* __restrict__ mat,
                                                  float* __restrict__ scal) {
  int bh = blockIdx.x, tid = threadIdx.x;
  int lane = tid & 63, wave = tid >> 6;
  const float* m = mat + (size_t)bh * 65536;
  float cs = 0.f, rs = 0.f;
  for (int i = 0; i < 256; i++) cs += m[i * 256 + tid];
  for (int j = 0; j < 256; j++) rs += m[tid * 256 + j];
  __shared__ float red[8];
  float cm = wredmax(cs);
  float rm = wredmax(rs);
  if (lane == 0) { red[wave] = cm; red[4 + wave] = rm; }
  __syncthreads();
  if (tid == 0) {
    float a = fmaxf(fmaxf(red[0], red[1]), fmaxf(red[2], red[3]));
    float b = fmaxf(fmaxf(red[4], red[5]), fmaxf(red[6], red[7]));
    atomicMax((int*)&scal[0], __float_as_int(a));
    atomicMax((int*)&scal[1], __float_as_int(b));
  }
}

__global__ __launch_bounds__(256) void pinv_init(const float* __restrict__ mat,
                                                 const float* __restrict__ scal,
                                                 float* __restrict__ z,
                                                 float* __restrict__ zT) {
  size_t idx = (size_t)blockIdx.x * 256 + threadIdx.x;
  int bh = (int)(idx >> 16);
  int i = (int)((idx >> 8) & 255), j = (int)(idx & 255);
  float s = 1.0f / (scal[0] * scal[1]);
  float val = mat[idx] * s;
  zT[idx] = val;
  z[((size_t)bh << 16) + ((size_t)j << 8) + i] = val;
}

// ---------------- attn3 (MFMA flash): w3T[bh][64][256] = (softmax(q_l k^T) v)^T ----------------
__global__ __launch_bounds__(256) void attn3_mfma(const float* __restrict__ q_l,
                                                  const u16* __restrict__ k,
                                                  const u16* __restrict__ vT,
                                                  float* __restrict__ w3T) {
  __shared__ __align__(16) u16 kb[2][64][72];
  __shared__ __align__(16) u16 vtb[2][64][72];
  __shared__ __align__(16) u16 Pb[64][72];
  int tid = threadIdx.x, lane = tid & 63, wv = tid >> 6;
  int l15 = lane & 15, g = lane >> 4;
  int bh = blockIdx.y, r0 = blockIdx.x * 64;
  // A-frags: q_l rows r0 + wv*16 + l15 (f32 -> bf16)
  const float* qlp = q_l + ((size_t)bh * 256 + r0 + wv * 16 + l15) * 64 + 8 * g;
  bf16x8 aq[2];
#pragma unroll
  for (int ks = 0; ks < 2; ks++) {
    f32x4 lo = *(const f32x4*)(qlp + 32 * ks);
    f32x4 hi = *(const f32x4*)(qlp + 32 * ks + 4);
    u32x4 u = {pk2(lo[0], lo[1]), pk2(lo[2], lo[3]), pk2(hi[0], hi[1]), pk2(hi[2], hi[3])};
    aq[ks] = __builtin_bit_cast(bf16x8, u);
  }
  int sr = tid >> 2, sc = (tid & 3) * 16;
  const u16* kbase = k + ((size_t)bh * 4096 + sr) * 64 + sc;
  const u16* vbase = vT + ((size_t)bh * 64 + sr) * 4096 + sc;
  u32x4 gk0 = *(const u32x4*)kbase, gk1 = *(const u32x4*)(kbase + 8);
  u32x4 gv0 = *(const u32x4*)vbase, gv1 = *(const u32x4*)(vbase + 8);
  *(u32x4*)&kb[0][sr][sc] = gk0;
  *(u32x4*)&kb[0][sr][sc + 8] = gk1;
  *(u32x4*)&vtb[0][sr][sc] = gv0;
  *(u32x4*)&vtb[0][sr][sc + 8] = gv1;
  __syncthreads();
  f32x4 mreg = {-1e30f, -1e30f, -1e30f, -1e30f};
  f32x4 lreg = {};
  f32x4 oacc[4] = {};
  for (int t = 0; t < 64; t++) {
    int cur = t & 1;
    if (t < 63) {
      size_t off = (size_t)(t + 1) * 64;
      gk0 = *(const u32x4*)(kbase + off * 64);
      gk1 = *(const u32x4*)(kbase + off * 64 + 8);
      gv0 = *(const u32x4*)(vbase + off);
      gv1 = *(const u32x4*)(vbase + off + 8);
    }
    // S = q_l @ k_tile^T   (16 rows x 64 cols per wave)
    f32x4 sa[4] = {};
#pragma unroll
    for (int ks = 0; ks < 2; ks++)
#pragma unroll
      for (int nf = 0; nf < 4; nf++) {
        bf16x8 b = lds_frag(&kb[cur][nf * 16 + l15][8 * g + 32 * ks]);
        sa[nf] = mfma16(aq[ks], b, sa[nf]);
      }
    // online softmax (rows local = 4g+r)
    f32x4 mn, corr;
#pragma unroll
    for (int r = 0; r < 4; r++) {
      float m_ = fmaxf(fmaxf(sa[0][r], sa[1][r]), fmaxf(sa[2][r], sa[3][r]));
#pragma unroll
      for (int msk = 1; msk < 16; msk <<= 1) m_ = fmaxf(m_, __shfl_xor(m_, msk));
      mn[r] = fmaxf(mreg[r], m_);
      corr[r] = __expf(mreg[r] - mn[r]);
      mreg[r] = mn[r];
    }
    f32x4 ps = {};
#pragma unroll
    for (int nf = 0; nf < 4; nf++)
#pragma unroll
      for (int r = 0; r < 4; r++) {
        sa[nf][r] = __expf(sa[nf][r] - mn[r]);
        ps[r] += sa[nf][r];
      }
#pragma unroll
    for (int r = 0; r < 4; r++) {
#pragma unroll
      for (int msk = 1; msk < 16; msk <<= 1) ps[r] += __shfl_xor(ps[r], msk);
      lreg[r] = lreg[r] * corr[r] + ps[r];
    }
#pragma unroll
    for (int nf = 0; nf < 4; nf++) oacc[nf] *= corr;
    // P -> LDS (bf16), then same-wave read as A-frags
#pragma unroll
    for (int nf = 0; nf < 4; nf++)
#pragma unroll
      for (int r = 0; r < 4; r++)
        Pb[wv * 16 + 4 * g + r][nf * 16 + l15] = f2b(sa[nf][r]);
    asm volatile("s_waitcnt lgkmcnt(0)" ::: "memory");
    __builtin_amdgcn_sched_barrier(0);
    bf16x8 ap0 = lds_frag(&Pb[wv * 16 + l15][8 * g]);
    bf16x8 ap1 = lds_frag(&Pb[wv * 16 + l15][8 * g + 32]);
#pragma unroll
    for (int nf = 0; nf < 4; nf++) {
      bf16x8 b0 = lds_frag(&vtb[cur][nf * 16 + l15][8 * g]);
      bf16x8 b1 = lds_frag(&vtb[cur][nf * 16 + l15][8 * g + 32]);
      oacc[nf] = mfma16(ap0, b0, oacc[nf]);
      oacc[nf] = mfma16(ap1, b1, oacc[nf]);
    }
    __syncthreads();
    if (t < 63) {
      int nb = cur ^ 1;
      *(u32x4*)&kb[nb][sr][sc] = gk0;
      *(u32x4*)&kb[nb][sr][sc + 8] = gk1;
      *(u32x4*)&vtb[nb][sr][sc] = gv0;
      *(u32x4*)&vtb[nb][sr][sc + 8] = gv1;
    }
    __syncthreads();
  }
#pragma unroll
  for (int nf = 0; nf < 4; nf++)
#pragma unroll
    for (int r = 0; r < 4; r++)
      w3T[((size_t)bh * 64 + nf * 16 + l15) * 256 + r0 + wv * 16 + 4 * g + r] =
          oacc[nf][r] / lreg[r];
}

// ---------------- attn1 (MFMA) + depthwise-conv residual -> out_h bf16 ----------------
__global__ __launch_bounds__(256) void attn1_mfma(const u16* __restrict__ q,
                                                  const float* __restrict__ k_l,
                                                  const float* __restrict__ zw,
                                                  const u16* __restrict__ v,
                                                  const float* __restrict__ rker,
                                                  u16* __restrict__ out_h) {
  __shared__ __align__(16) u16 regA[18432];  // kl[256][72] -> zwT[64][264] -> vlds[96][72]
  __shared__ __align__(16) u16 Pl[64][264];
  __shared__ float ker[33];
  u16(*kl)[72] = (u16(*)[72])regA;
  u16(*zwT)[264] = (u16(*)[264])regA;
  u16(*vlds)[72] = (u16(*)[72])regA;
  int tid = threadIdx.x, lane = tid & 63, wv = tid >> 6;
  int l15 = lane & 15, g = lane >> 4;
  int bh = blockIdx.y, h = bh & 7;
  int i0 = blockIdx.x * 64;
  // A-frags from global q (rows i0 + wv*16 + l15)
  const u16* qp = q + ((size_t)bh * 4096 + i0 + wv * 16 + l15) * 64 + 8 * g;
  bf16x8 aq0 = __builtin_bit_cast(bf16x8, *(const u32x4*)qp);
  bf16x8 aq1 = __builtin_bit_cast(bf16x8, *(const u32x4*)(qp + 32));
  // stage k_l (f32 -> bf16), one row per thread
  {
    const float* klr = k_l + ((size_t)bh * 256 + tid) * 64;
#pragma unroll
    for (int e = 0; e < 16; e++) {
      f32x4 vv = *(const f32x4*)(klr + 4 * e);
      *(u32*)&kl[tid][4 * e] = pk2(vv[0], vv[1]);
      *(u32*)&kl[tid][4 * e + 2] = pk2(vv[2], vv[3]);
    }
    if (tid < 33) ker[tid] = rker[h * 33 + tid];
  }
  __syncthreads();
  // S = q @ k_l^T : 16 x 256 per wave
  f32x4 sacc[16] = {};
#pragma unroll
  for (int nf = 0; nf < 16; nf++) {
    bf16x8 b0 = lds_frag(&kl[nf * 16 + l15][8 * g]);
    bf16x8 b1 = lds_frag(&kl[nf * 16 + l15][8 * g + 32]);
    sacc[nf] = mfma16(aq0, b0, sacc[nf]);
    sacc[nf] = mfma16(aq1, b1, sacc[nf]);
  }
  __syncthreads();  // done with kl; region A reused for zwT
  // issue zw loads (2 rows per thread, half of d each)
  int jp = 2 * (tid & 127), dh2 = (tid >> 7) * 32;
  const float* z0 = zw + ((size_t)bh * 256 + jp) * 64 + dh2;
  const float* z1 = z0 + 64;
  f32x4 za[8], zb[8];
#pragma unroll
  for (int e = 0; e < 8; e++) {
    za[e] = *(const f32x4*)(z0 + 4 * e);
    zb[e] = *(const f32x4*)(z1 + 4 * e);
  }
  // issue v loads (rows i0-16 .. i0+79)
  int vrow = tid >> 1, vh = tid & 1, gr = i0 - 16 + vrow;
  u32x4 vreg[4] = {};
  if (tid < 192 && gr >= 0 && gr < 4096) {
    const u16* vs = v + ((size_t)bh * 4096 + gr) * 64 + vh * 32;
#pragma unroll
    for (int e = 0; e < 4; e++) vreg[e] = *(const u32x4*)(vs + 8 * e);
  }
  // softmax (rows local = 4g+r within wave strip)
  f32x4 mx;
#pragma unroll
  for (int r = 0; r < 4; r++) {
    float m_ = sacc[0][r];
#pragma unroll
    for (int nf = 1; nf < 16; nf++) m_ = fmaxf(m_, sacc[nf][r]);
#pragma unroll
    for (int msk = 1; msk < 16; msk <<= 1) m_ = fmaxf(m_, __shfl_xor(m_, msk));
    mx[r] = m_;
  }
  f32x4 ls = {};
#pragma unroll
  for (int nf = 0; nf < 16; nf++)
#pragma unroll
    for (int r = 0; r < 4; r++) {
      sacc[nf][r] = __expf(sacc[nf][r] - mx[r]);
      ls[r] += sacc[nf][r];
    }
  f32x4 invl;
#pragma unroll
  for (int r = 0; r < 4; r++) {
#pragma unroll
    for (int msk = 1; msk < 16; msk <<= 1) ls[r] += __shfl_xor(ls[r], msk);
    invl[r] = 1.0f / ls[r];
  }
  // write P (unnormalized bf16)
#pragma unroll
  for (int nf = 0; nf < 16; nf++)
#pragma unroll
    for (int r = 0; r < 4; r++) Pl[wv * 16 + 4 * g + r][nf * 16 + l15] = f2b(sacc[nf][r]);
  // write zwT (transposed, bf16, packed pairs)
#pragma unroll
  for (int e = 0; e < 8; e++)
#pragma unroll
    for (int u = 0; u < 4; u++) *(u32*)&zwT[dh2 + 4 * e + u][jp] = pk2(za[e][u], zb[e][u]);
  __syncthreads();
  // PV: out(16x64) = P(16x256) @ zw(256x64)
  bf16x8 ap[8];
#pragma unroll
  for (int ks = 0; ks < 8; ks++) ap[ks] = lds_frag(&Pl[wv * 16 + l15][8 * g + 32 * ks]);
  f32x4 oacc[4] = {};
#pragma unroll
  for (int nf = 0; nf < 4; nf++)
#pragma unroll
    for (int ks = 0; ks < 8; ks++) {
      bf16x8 b = lds_frag(&zwT[nf * 16 + l15][8 * g + 32 * ks]);
      oacc[nf] = mfma16(ap[ks], b, oacc[nf]);
    }
  __syncthreads();  // done with zwT; region A reused for v window
  if (tid < 192) {
#pragma unroll
    for (int e = 0; e < 4; e++) *(u32x4*)&vlds[vrow][vh * 32 + 8 * e] = vreg[e];
  }
  __syncthreads();
  // conv residual + combine, bounce through Pl for vectorized store
  int base = wv * 16 + 4 * g;
#pragma unroll
  for (int nf = 0; nf < 4; nf++) {
    int c = nf * 16 + l15;
    float win[36];
#pragma unroll
    for (int t = 0; t < 36; t++) win[t] = b2f(vlds[base + t][c]);
#pragma unroll
    for (int r = 0; r < 4; r++) {
      float res = 0.f;
#pragma unroll
      for (int t = 0; t < 33; t++) res += ker[t] * win[r + t];
      Pl[base + r][c] = f2b(oacc[nf][r] * invl[r] + res);
    }
  }
  __syncthreads();
  int row = tid >> 2, seg = (tid & 3) * 16;
  u32x4 o0 = *(u32x4*)&Pl[row][seg];
  u32x4 o1 = *(u32x4*)&Pl[row][seg + 8];
  u16* dst = out_h + ((size_t)bh * 4096 + i0 + row) * 64 + seg;
  *(u32x4*)dst = o0;
  *(u32x4*)(dst + 8) = o1;
}

extern "C" void kernel_launch(void* const* d_in, const int* in_sizes, int n_in,
                              void* d_out, int out_size, void* d_ws, size_t ws_size,
                              hipStream_t stream) {
  (void)in_sizes; (void)n_in; (void)out_size;
  const float* x = (const float*)d_in[0];
  const float* w_qkv = (const float*)d_in[1];
  const float* w_out = (const float*)d_in[2];
  const float* b_out = (const float*)d_in[3];
  const float* res_k = (const float*)d_in[4];
  const float* gamma = (const float*)d_in[5];
  const float* beta = (const float*)d_in[6];
  float* out = (float*)d_out;

  char* p = (char*)d_ws;
  auto alloc = [&](size_t bytes) {
    char* r = p;
    p += (bytes + 255) & ~(size_t)255;
    return r;
  };
  const size_t BH = 32;
  u16* xn = (u16*)alloc(BH * 4096 * 64 * 2);  // aliased: vT after qkv
  u16* vT = xn;
  u16* wTq = (u16*)alloc(1536 * 512 * 2);
  u16* wTo = (u16*)alloc(512 * 512 * 2);
  u16* q = (u16*)alloc(BH * 4096 * 64 * 2);
  u16* k = (u16*)alloc(BH * 4096 * 64 * 2);
  u16* v = (u16*)alloc(BH * 4096 * 64 * 2);
  float* q_l = (float*)alloc(BH * 256 * 64 * 4);
  float* k_l = (float*)alloc(BH * 256 * 64 * 4);
  float* mat = (float*)alloc(BH * 65536 * 4);
  float* z = (float*)alloc(BH * 65536 * 4);
  float* zT = (float*)alloc(BH * 65536 * 4);
  float* znew = (float*)alloc(BH * 65536 * 4);
  float* znewT = (float*)alloc(BH * 65536 * 4);
  char* slotB = alloc(4 * BH * 65536 * 4);  // mz,mzT,t2T,t4T; aliased: out_h
  float* mz = (float*)slotB;
  float* mzT = mz + BH * 65536;
  float* t2T = mzT + BH * 65536;
  float* t4T = t2T + BH * 65536;
  u16* out_h = (u16*)slotB;
  float* w3T = (float*)alloc(BH * 64 * 256 * 4);
  float* zw = (float*)alloc(BH * 256 * 64 * 4);
  float* scal = (float*)alloc(256);
  if ((size_t)(p - (char*)d_ws) > ws_size) return;  // insufficient workspace

  hipMemsetAsync(scal, 0, 8, stream);
  ln_k<<<16384, 256, 0, stream>>>(x, gamma, beta, xn);
  transpose_w<<<dim3(24, 8), 256, 0, stream>>>(w_qkv, wTq, 512, 1536);
  transpose_w<<<dim3(8, 8), 256, 0, stream>>>(w_out, wTo, 512, 512);
  gemm_bf16_nt<0><<<dim3(128, 12), 256, 0, stream>>>(xn, wTq, 512, q, k, v, nullptr,
                                                     nullptr, nullptr);
  landmark_mean<<<2048, 256, 0, stream>>>(q, q_l);
  landmark_mean<<<2048, 256, 0, stream>>>(k, k_l);
  transpose_k<<<dim3(64, 32), 256, 0, stream>>>(v, vT);  // vT aliases xn (xn dead)
  // attn2 logits: mat = q_l @ k_l^T
  gemm_f32_nt<<<dim3(4, 4, 32), 256, 0, stream>>>(q_l, k_l, mat, nullptr, 256, 256, 64,
                                                  16384, 16384, 65536, 0, 0.f, 1.f, 1.f, 1, 0);
  softmax256<<<2048, 256, 0, stream>>>(mat);
  pinv_scale<<<32, 256, 0, stream>>>(mat, scal);
  pinv_init<<<8192, 256, 0, stream>>>(mat, scal, z, zT);
  float* zc = z; float* zcT = zT; float* zn = znew; float* znT = znewT;
  for (int it = 0; it < 6; it++) {
    gemm_f32_nt<<<dim3(4, 4, 32), 256, 0, stream>>>(mat, zcT, mz, mzT, 256, 256, 256,
                                                    65536, 65536, 65536, 65536, 0.f, 1.f, 1.f, 1, 1);
    gemm_f32_nt<<<dim3(4, 4, 32), 256, 0, stream>>>(mz, mzT, nullptr, t2T, 256, 256, 256,
                                                    65536, 65536, 65536, 65536, 7.f, -1.f, 1.f, 0, 1);
    gemm_f32_nt<<<dim3(4, 4, 32), 256, 0, stream>>>(mz, t2T, nullptr, t4T, 256, 256, 256,
                                                    65536, 65536, 65536, 65536, 15.f, -1.f, 1.f, 0, 1);
    gemm_f32_nt<<<dim3(4, 4, 32), 256, 0, stream>>>(zc, t4T, zn, znT, 256, 256, 256,
                                                    65536, 65536, 65536, 65536, 13.f, -1.f, 0.25f, 1, 1);
    float* t;
    t = zc; zc = zn; zn = t;
    t = zcT; zcT = znT; znT = t;
  }
  attn3_mfma<<<dim3(4, 32), 256, 0, stream>>>(q_l, k, vT, w3T);
  // zw = z @ w3
  gemm_f32_nt<<<dim3(4, 1, 32), 256, 0, stream>>>(zc, w3T, zw, nullptr, 256, 64, 256,
                                                  65536, 16384, 16384, 0, 0.f, 1.f, 1.f, 1, 0);
  attn1_mfma<<<dim3(64, 32), 256, 0, stream>>>(q, k_l, zw, v, res_k, out_h);
  gemm_bf16_nt<1><<<dim3(128, 4), 256, 0, stream>>>(out_h, wTo, 512, nullptr, nullptr,
                                                    nullptr, x, b_out, out);
}